// Round 5
// baseline (360.970 us; speedup 1.0000x reference)
//
#include <hip/hip_runtime.h>

// Tucker conv, 2-kernel MFMA pipeline, v5:
//   stageA: UNCHANGED from v3/v4 (isolation; gets counters next round).
//   fusedBC: v4 LDS factor cache kept, but 512 threads / 8 waves per block
//     (2 waves/SIMD instead of 1). Two wave-groups split the 7-row loop 4/3,
//     each with its own yt buffer. yt B-frag reads hoisted out of the g-loop.

typedef __attribute__((ext_vector_type(8))) short short8;
typedef __attribute__((ext_vector_type(4))) short short4v;
typedef __attribute__((ext_vector_type(4))) float f32x4;

#define B_    32
#define CIN_  256
#define H_    56
#define W_    56
#define HW_   (H_*W_)          // 3136
#define COUT_ 256
#define HP_   58
#define WP_   64

// workspace byte offsets (16B-aligned)
#define OFF_FIRSTW  0u                        // bf16 [64][256]        32768 B
#define OFF_COREW   32768u                    // bf16 [9][64][64]      73728 B
#define OFF_LASTW   106496u                   // bf16 [256][64]        32768 B
#define OFF_X1P     139264u                   // bf16 [32][58][64][64] 15204352 B (+slack)

__device__ __forceinline__ unsigned short f2bf(float f) {
  union { float f; unsigned int u; } v; v.f = f;
  return (unsigned short)((v.u + 0x7FFFu + ((v.u >> 16) & 1u)) >> 16);
}
__device__ __forceinline__ short4v pack4(f32x4 a) {
  short4v p;
  p.x = (short)f2bf(a.x); p.y = (short)f2bf(a.y);
  p.z = (short)f2bf(a.z); p.w = (short)f2bf(a.w);
  return p;
}

// ---- prep: cast/transpose small factors to bf16 ----
__global__ __launch_bounds__(256) void prep_kernel(
    const float* __restrict__ first,   // [64][256]
    const float* __restrict__ core,    // [64][64][3][3]
    const float* __restrict__ last,    // [256][64]
    unsigned short* __restrict__ ws16) {
  int i = blockIdx.x * 256 + threadIdx.x;   // 69632 threads
  if (i < 16384) {
    ws16[(OFF_FIRSTW >> 1) + i] = f2bf(first[i]);                 // [s][c]
  } else if (i < 53248) {
    int j = i - 16384;                                            // coreW[t][r][s]
    int t = j >> 12, r = (j >> 6) & 63, s = j & 63;
    ws16[(OFF_COREW >> 1) + j] = f2bf(core[(r * 64 + s) * 9 + t]);
  } else {
    ws16[(OFF_LASTW >> 1) + (i - 53248)] = f2bf(last[i - 53248]); // [o][r]
  }
}

// ---- stage A: one block per (b, h'); pipelined strided loads, MFMA,
//      wave-local LDS transpose -> coalesced x1p stores. (unchanged)
#define SATS 72   // LDS halfs per wp-entry (64 s + 8 pad)
__global__ __launch_bounds__(256, 6) void stageA_kernel(
    const float* __restrict__ x,
    unsigned short* __restrict__ ws16) {
  __shared__ unsigned short st[4][16][SATS];   // 9216 B, wave-local
  const unsigned short* firstW = ws16 + (OFF_FIRSTW >> 1);
  unsigned short* x1p = ws16 + (OFF_X1P >> 1);

  int tid = threadIdx.x, wave = tid >> 6, lane = tid & 63;
  int quad = lane >> 4, l15 = lane & 15;
  int bid0 = blockIdx.x;                 // 1856 = 8*232
  int bid = (bid0 & 7) * 232 + (bid0 >> 3);   // XCD-contiguous swizzle
  int b = bid / HP_, hp = bid - b * HP_;
  size_t rowbase = (size_t)(b * HP_ + hp) * (WP_ * 64);

  if (hp == 0 || hp == HP_ - 1) {       // halo rows: true zeros
    short8 z = {0,0,0,0,0,0,0,0};
#pragma unroll
    for (int i = 0; i < 2; ++i)
      *(short8*)(x1p + rowbase + (size_t)(tid + i * 256) * 8) = z;
    return;
  }

  int h = hp - 1;
  int wp = wave * 16 + l15;             // w' column this lane produces: 0..63
  bool valid = (wp >= 1 && wp <= 56);   // w'=0 and 57..63 are halo zeros
  int wsrc = valid ? (wp - 1) : 0;      // clamp keeps loads in-bounds
  const float* xcol = x + (size_t)b * (CIN_ * HW_) + h * W_ + wsrc;

  f32x4 acc[4] = {{0,0,0,0},{0,0,0,0},{0,0,0,0},{0,0,0,0}};
  float xv[2][8];
#pragma unroll
  for (int j = 0; j < 8; ++j) xv[0][j] = xcol[(size_t)(quad * 8 + j) * HW_];

#pragma unroll
  for (int cc = 0; cc < 8; ++cc) {       // fully unrolled: indices static
    int cur = cc & 1;
    if (cc < 7) {                        // issue next chunk's loads first
      const float* p = xcol + (size_t)((cc + 1) * 32 + quad * 8) * HW_;
#pragma unroll
      for (int j = 0; j < 8; ++j) xv[cur ^ 1][j] = p[(size_t)j * HW_];
    }
    short8 bfrag;
#pragma unroll
    for (int j = 0; j < 8; ++j) bfrag[j] = (short)f2bf(xv[cur][j]);
#pragma unroll
    for (int mt = 0; mt < 4; ++mt) {
      short8 af = *(const short8*)(firstW + (mt * 16 + l15) * CIN_ + cc * 32 + quad * 8);
      acc[mt] = __builtin_amdgcn_mfma_f32_16x16x32_bf16(af, bfrag, acc[mt], 0, 0, 0);
    }
  }

  // wave-local transpose: st[wave][wp_local][s]; invalid lanes deposit zeros
  short4v zero4 = {0,0,0,0};
#pragma unroll
  for (int mt = 0; mt < 4; ++mt) {
    short4v r = valid ? pack4(acc[mt]) : zero4;
    *(short4v*)&st[wave][l15][mt * 16 + quad * 4] = r;
  }
  // readback linear, store coalesced (1KB contiguous per instruction)
#pragma unroll
  for (int i = 0; i < 2; ++i) {
    int idx = i * 512 + lane * 8;        // half-index within wave's 16x64 tile
    int r = idx >> 6, s0 = idx & 63;
    short8 v = *(const short8*)&st[wave][r][s0];
    *(short8*)(x1p + rowbase + (size_t)wave * 1024 + idx) = v;
  }
}

// ---- fused B+C v5: 256 blocks x 512 threads; factors in LDS; 2 row-groups ----
#define CWP 72            // padded row stride (halfs) for cw/lw fragments
#define XTS 72            // yt halfs per w-entry (64 r + 8 pad)
__global__ __launch_bounds__(512, 2) void fusedBC_kernel(
    const unsigned short* __restrict__ ws16,
    const float* __restrict__ bias,
    float* __restrict__ out) {
  __shared__ unsigned short cw[9 * 64 * CWP];   // 82944 B  coreW [t][r][s]
  __shared__ unsigned short lw[256 * CWP];      // 36864 B  lastW [o][r]
  __shared__ unsigned short yt[2][64 * XTS];    // 18432 B  transpose buf/group
  const unsigned short* coreW = ws16 + (OFF_COREW >> 1);
  const unsigned short* lastW = ws16 + (OFF_LASTW >> 1);
  const unsigned short* x1p   = ws16 + (OFF_X1P >> 1);

  int tid = threadIdx.x, wave = tid >> 6, lane = tid & 63;
  int quad = lane >> 4, l15 = lane & 15;
  int grp = wave >> 2, wv = wave & 3;   // 2 groups x 4 waves
  int bid = blockIdx.x;                 // 256 = 32 b * 8 hgroups
  int b = bid >> 3, hg = bid & 7;
  int h0 = hg * 7;                      // rows h0..h0+6 (8*7 = 56 exactly)

  // ---- one-time factor staging into LDS (row stride 64 -> CWP)
  for (int ci = tid; ci < 9 * 64 * 8; ci += 512) {        // coreW: 4608 chunks
    int row = ci >> 3, s0 = (ci & 7) * 8;
    *(short8*)&cw[row * CWP + s0] = *(const short8*)(coreW + row * 64 + s0);
  }
  for (int ci = tid; ci < 256 * 8; ci += 512) {           // lastW: 2048 chunks
    int row = ci >> 3, s0 = (ci & 7) * 8;
    *(short8*)&lw[row * CWP + s0] = *(const short8*)(lastW + row * 64 + s0);
  }
  __syncthreads();

  int w = wv * 16 + l15;                // 0..63 (w>=56 garbage, masked at store)
  unsigned short* ytg = &yt[grp][0];

  int hrBeg = grp ? 4 : 0;
  int hrEnd = grp ? 7 : 4;
  for (int hr = hrBeg; hr < hrEnd; ++hr) {
    int h = h0 + hr;
    // per-lane base into x1p: rows h..h+2, col w+kw, 16B contiguous k
    const unsigned short* xw = x1p + (size_t)(b * HP_ + h) * (WP_ * 64)
                               + (size_t)w * 64 + quad * 8;

    // ---- B-phase: y1[r=64][w] = sum_{t,s} core * x1; prefetch t+1 frags
    f32x4 acc[4] = {{0,0,0,0},{0,0,0,0},{0,0,0,0},{0,0,0,0}};
    short8 bc0 = *(const short8*)(xw);
    short8 bc1 = *(const short8*)(xw + 32);
#pragma unroll
    for (int t = 0; t < 9; ++t) {
      short8 bn0, bn1;
      if (t < 8) {
        int kh2 = (t + 1) / 3, kw2 = (t + 1) - kh2 * 3;
        const unsigned short* p = xw + (size_t)(kh2 * WP_ + kw2) * 64;
        bn0 = *(const short8*)p;
        bn1 = *(const short8*)(p + 32);
      }
#pragma unroll
      for (int mt = 0; mt < 4; ++mt) {
        short8 af = *(const short8*)&cw[(t * 64 + mt * 16 + l15) * CWP + quad * 8];
        acc[mt] = __builtin_amdgcn_mfma_f32_16x16x32_bf16(af, bc0, acc[mt], 0, 0, 0);
      }
#pragma unroll
      for (int mt = 0; mt < 4; ++mt) {
        short8 af = *(const short8*)&cw[(t * 64 + mt * 16 + l15) * CWP + 32 + quad * 8];
        acc[mt] = __builtin_amdgcn_mfma_f32_16x16x32_bf16(af, bc1, acc[mt], 0, 0, 0);
      }
      if (t < 8) { bc0 = bn0; bc1 = bn1; }
    }

    // ---- wave-local transpose through group's yt: yt[w][r] (same wave
    //      writes/reads only its own w-columns; in-wave LDS ordering suffices)
#pragma unroll
    for (int mt = 0; mt < 4; ++mt)
      *(short4v*)&ytg[w * XTS + mt * 16 + quad * 4] = pack4(acc[mt]);

    // read back this lane's y-row fragments ONCE (reused across 4 o-groups)
    short8 yb0 = *(const short8*)&ytg[w * XTS + quad * 8];
    short8 yb1 = *(const short8*)&ytg[w * XTS + 32 + quad * 8];

    // ---- C-phase, streamed: 4 o-groups of 64, factors from LDS
    float* ob = out + (size_t)b * (COUT_ * HW_) + h * W_ + w;
#pragma unroll
    for (int g = 0; g < 4; ++g) {
      f32x4 a2[4] = {{0,0,0,0},{0,0,0,0},{0,0,0,0},{0,0,0,0}};
#pragma unroll
      for (int m = 0; m < 4; ++m) {
        short8 af = *(const short8*)&lw[(g * 64 + m * 16 + l15) * CWP + quad * 8];
        a2[m] = __builtin_amdgcn_mfma_f32_16x16x32_bf16(af, yb0, a2[m], 0, 0, 0);
      }
#pragma unroll
      for (int m = 0; m < 4; ++m) {
        short8 af = *(const short8*)&lw[(g * 64 + m * 16 + l15) * CWP + 32 + quad * 8];
        a2[m] = __builtin_amdgcn_mfma_f32_16x16x32_bf16(af, yb1, a2[m], 0, 0, 0);
      }
      if (w < W_) {
#pragma unroll
        for (int m = 0; m < 4; ++m) {
          int o = g * 64 + m * 16 + quad * 4;
          float4 bv = *(const float4*)(bias + o);
          ob[(size_t)(o + 0) * HW_] = a2[m].x + bv.x;
          ob[(size_t)(o + 1) * HW_] = a2[m].y + bv.y;
          ob[(size_t)(o + 2) * HW_] = a2[m].z + bv.z;
          ob[(size_t)(o + 3) * HW_] = a2[m].w + bv.w;
        }
      }
    }
  }
}

extern "C" void kernel_launch(void* const* d_in, const int* in_sizes, int n_in,
                              void* d_out, int out_size, void* d_ws, size_t ws_size,
                              hipStream_t stream) {
  const float* x     = (const float*)d_in[0];
  const float* first = (const float*)d_in[1];
  const float* core  = (const float*)d_in[2];
  const float* last  = (const float*)d_in[3];
  const float* bias  = (const float*)d_in[4];
  float* out = (float*)d_out;
  unsigned short* ws16 = (unsigned short*)d_ws;

  prep_kernel<<<272, 256, 0, stream>>>(first, core, last, ws16);
  stageA_kernel<<<B_ * HP_, 256, 0, stream>>>(x, ws16);
  fusedBC_kernel<<<256, 512, 0, stream>>>(ws16, bias, out);
}

// Round 6
// 263.846 us; speedup vs baseline: 1.3681x; 1.3681x over previous
//
#include <hip/hip_runtime.h>

// Tucker conv, 2-kernel MFMA pipeline, v6:
//   stageA: UNCHANGED from v3/v4/v5.
//   fusedBC: 256 blocks x 512 threads (8 waves = 2/SIMD); LDS factor cache
//     kept. All 8 waves cooperate on the SAME h row: B-phase split by
//     (r-half x w-quarter), C-phase split by (o-half x w-quarter). Per-wave
//     register footprint halved vs v5 (acc[2], 2 o-groups) so 128 VGPR fits
//     WITHOUT scratch spill (v5's regression: 240MB of spill traffic).
//     yt transpose double-buffered; one barrier per row.

typedef __attribute__((ext_vector_type(8))) short short8;
typedef __attribute__((ext_vector_type(4))) short short4v;
typedef __attribute__((ext_vector_type(4))) float f32x4;

#define B_    32
#define CIN_  256
#define H_    56
#define W_    56
#define HW_   (H_*W_)          // 3136
#define COUT_ 256
#define HP_   58
#define WP_   64

// workspace byte offsets (16B-aligned)
#define OFF_FIRSTW  0u                        // bf16 [64][256]        32768 B
#define OFF_COREW   32768u                    // bf16 [9][64][64]      73728 B
#define OFF_LASTW   106496u                   // bf16 [256][64]        32768 B
#define OFF_X1P     139264u                   // bf16 [32][58][64][64] 15204352 B (+slack)

__device__ __forceinline__ unsigned short f2bf(float f) {
  union { float f; unsigned int u; } v; v.f = f;
  return (unsigned short)((v.u + 0x7FFFu + ((v.u >> 16) & 1u)) >> 16);
}
__device__ __forceinline__ short4v pack4(f32x4 a) {
  short4v p;
  p.x = (short)f2bf(a.x); p.y = (short)f2bf(a.y);
  p.z = (short)f2bf(a.z); p.w = (short)f2bf(a.w);
  return p;
}

// ---- prep: cast/transpose small factors to bf16 ----
__global__ __launch_bounds__(256) void prep_kernel(
    const float* __restrict__ first,   // [64][256]
    const float* __restrict__ core,    // [64][64][3][3]
    const float* __restrict__ last,    // [256][64]
    unsigned short* __restrict__ ws16) {
  int i = blockIdx.x * 256 + threadIdx.x;   // 69632 threads
  if (i < 16384) {
    ws16[(OFF_FIRSTW >> 1) + i] = f2bf(first[i]);                 // [s][c]
  } else if (i < 53248) {
    int j = i - 16384;                                            // coreW[t][r][s]
    int t = j >> 12, r = (j >> 6) & 63, s = j & 63;
    ws16[(OFF_COREW >> 1) + j] = f2bf(core[(r * 64 + s) * 9 + t]);
  } else {
    ws16[(OFF_LASTW >> 1) + (i - 53248)] = f2bf(last[i - 53248]); // [o][r]
  }
}

// ---- stage A: one block per (b, h'); pipelined strided loads, MFMA,
//      wave-local LDS transpose -> coalesced x1p stores. (unchanged)
#define SATS 72   // LDS halfs per wp-entry (64 s + 8 pad)
__global__ __launch_bounds__(256, 6) void stageA_kernel(
    const float* __restrict__ x,
    unsigned short* __restrict__ ws16) {
  __shared__ unsigned short st[4][16][SATS];   // 9216 B, wave-local
  const unsigned short* firstW = ws16 + (OFF_FIRSTW >> 1);
  unsigned short* x1p = ws16 + (OFF_X1P >> 1);

  int tid = threadIdx.x, wave = tid >> 6, lane = tid & 63;
  int quad = lane >> 4, l15 = lane & 15;
  int bid0 = blockIdx.x;                 // 1856 = 8*232
  int bid = (bid0 & 7) * 232 + (bid0 >> 3);   // XCD-contiguous swizzle
  int b = bid / HP_, hp = bid - b * HP_;
  size_t rowbase = (size_t)(b * HP_ + hp) * (WP_ * 64);

  if (hp == 0 || hp == HP_ - 1) {       // halo rows: true zeros
    short8 z = {0,0,0,0,0,0,0,0};
#pragma unroll
    for (int i = 0; i < 2; ++i)
      *(short8*)(x1p + rowbase + (size_t)(tid + i * 256) * 8) = z;
    return;
  }

  int h = hp - 1;
  int wp = wave * 16 + l15;             // w' column this lane produces: 0..63
  bool valid = (wp >= 1 && wp <= 56);   // w'=0 and 57..63 are halo zeros
  int wsrc = valid ? (wp - 1) : 0;      // clamp keeps loads in-bounds
  const float* xcol = x + (size_t)b * (CIN_ * HW_) + h * W_ + wsrc;

  f32x4 acc[4] = {{0,0,0,0},{0,0,0,0},{0,0,0,0},{0,0,0,0}};
  float xv[2][8];
#pragma unroll
  for (int j = 0; j < 8; ++j) xv[0][j] = xcol[(size_t)(quad * 8 + j) * HW_];

#pragma unroll
  for (int cc = 0; cc < 8; ++cc) {       // fully unrolled: indices static
    int cur = cc & 1;
    if (cc < 7) {                        // issue next chunk's loads first
      const float* p = xcol + (size_t)((cc + 1) * 32 + quad * 8) * HW_;
#pragma unroll
      for (int j = 0; j < 8; ++j) xv[cur ^ 1][j] = p[(size_t)j * HW_];
    }
    short8 bfrag;
#pragma unroll
    for (int j = 0; j < 8; ++j) bfrag[j] = (short)f2bf(xv[cur][j]);
#pragma unroll
    for (int mt = 0; mt < 4; ++mt) {
      short8 af = *(const short8*)(firstW + (mt * 16 + l15) * CIN_ + cc * 32 + quad * 8);
      acc[mt] = __builtin_amdgcn_mfma_f32_16x16x32_bf16(af, bfrag, acc[mt], 0, 0, 0);
    }
  }

  // wave-local transpose: st[wave][wp_local][s]; invalid lanes deposit zeros
  short4v zero4 = {0,0,0,0};
#pragma unroll
  for (int mt = 0; mt < 4; ++mt) {
    short4v r = valid ? pack4(acc[mt]) : zero4;
    *(short4v*)&st[wave][l15][mt * 16 + quad * 4] = r;
  }
  // readback linear, store coalesced (1KB contiguous per instruction)
#pragma unroll
  for (int i = 0; i < 2; ++i) {
    int idx = i * 512 + lane * 8;        // half-index within wave's 16x64 tile
    int r = idx >> 6, s0 = idx & 63;
    short8 v = *(const short8*)&st[wave][r][s0];
    *(short8*)(x1p + rowbase + (size_t)wave * 1024 + idx) = v;
  }
}

// ---- fused B+C v6: 256 blocks x 512 threads; 8 waves cooperate per row ----
#define CWP 72            // padded row stride (halfs) for cw/lw fragments
#define XTS 72            // yt halfs per w-entry (64 r + 8 pad)
__global__ __launch_bounds__(512) void fusedBC_kernel(
    const unsigned short* __restrict__ ws16,
    const float* __restrict__ bias,
    float* __restrict__ out) {
  __shared__ unsigned short cw[9 * 64 * CWP];   // 82944 B  coreW [t][r][s]
  __shared__ unsigned short lw[256 * CWP];      // 36864 B  lastW [o][r]
  __shared__ unsigned short yt[2][64 * XTS];    // 18432 B  transpose dbuf
  const unsigned short* coreW = ws16 + (OFF_COREW >> 1);
  const unsigned short* lastW = ws16 + (OFF_LASTW >> 1);
  const unsigned short* x1p   = ws16 + (OFF_X1P >> 1);

  int tid = threadIdx.x, wave = tid >> 6, lane = tid & 63;
  int quad = lane >> 4, l15 = lane & 15;
  int wq = wave & 3, oh = wave >> 2;    // w-quarter, r/o-half
  int bid = blockIdx.x;                 // 256 = 32 b * 8 hgroups
  int b = bid >> 3, hg = bid & 7;
  int h0 = hg * 7;                      // rows h0..h0+6 (8*7 = 56 exactly)

  // ---- one-time factor staging into LDS (row stride 64 -> CWP)
  for (int ci = tid; ci < 9 * 64 * 8; ci += 512) {        // coreW
    int row = ci >> 3, s0 = (ci & 7) * 8;
    *(short8*)&cw[row * CWP + s0] = *(const short8*)(coreW + row * 64 + s0);
  }
  for (int ci = tid; ci < 256 * 8; ci += 512) {           // lastW
    int row = ci >> 3, s0 = (ci & 7) * 8;
    *(short8*)&lw[row * CWP + s0] = *(const short8*)(lastW + row * 64 + s0);
  }
  __syncthreads();

  int w = wq * 16 + l15;                // 0..63 (w>=56 garbage, masked at store)

  for (int hr = 0; hr < 7; ++hr) {
    int h = h0 + hr;
    unsigned short* ytc = &yt[hr & 1][0];
    // per-lane base into x1p: rows h..h+2, col w+kw, 16B contiguous k
    const unsigned short* xw = x1p + (size_t)(b * HP_ + h) * (WP_ * 64)
                               + (size_t)w * 64 + quad * 8;

    // ---- B-phase: this wave computes r-half oh (mt = oh*2 + {0,1})
    f32x4 acc[2] = {{0,0,0,0},{0,0,0,0}};
    short8 bc0 = *(const short8*)(xw);
    short8 bc1 = *(const short8*)(xw + 32);
#pragma unroll
    for (int t = 0; t < 9; ++t) {
      short8 bn0, bn1;
      if (t < 8) {
        int kh2 = (t + 1) / 3, kw2 = (t + 1) - kh2 * 3;
        const unsigned short* p = xw + (size_t)(kh2 * WP_ + kw2) * 64;
        bn0 = *(const short8*)p;
        bn1 = *(const short8*)(p + 32);
      }
#pragma unroll
      for (int m2 = 0; m2 < 2; ++m2) {
        int mt = oh * 2 + m2;
        short8 af = *(const short8*)&cw[(t * 64 + mt * 16 + l15) * CWP + quad * 8];
        acc[m2] = __builtin_amdgcn_mfma_f32_16x16x32_bf16(af, bc0, acc[m2], 0, 0, 0);
      }
#pragma unroll
      for (int m2 = 0; m2 < 2; ++m2) {
        int mt = oh * 2 + m2;
        short8 af = *(const short8*)&cw[(t * 64 + mt * 16 + l15) * CWP + 32 + quad * 8];
        acc[m2] = __builtin_amdgcn_mfma_f32_16x16x32_bf16(af, bc1, acc[m2], 0, 0, 0);
      }
      if (t < 8) { bc0 = bn0; bc1 = bn1; }
    }

    // ---- transpose into yt[hr&1]: w column w gets r-half oh from this wave
#pragma unroll
    for (int m2 = 0; m2 < 2; ++m2) {
      int mt = oh * 2 + m2;
      *(short4v*)&ytc[w * XTS + mt * 16 + quad * 4] = pack4(acc[m2]);
    }
    __syncthreads();   // r-halves of yt come from different waves

    // ---- C-phase: this wave computes o-half oh (g = oh*2 + {0,1})
    short8 yb0 = *(const short8*)&ytc[w * XTS + quad * 8];
    short8 yb1 = *(const short8*)&ytc[w * XTS + 32 + quad * 8];

    float* ob = out + (size_t)b * (COUT_ * HW_) + h * W_ + w;
#pragma unroll
    for (int g2 = 0; g2 < 2; ++g2) {
      int g = oh * 2 + g2;
      f32x4 a2[4] = {{0,0,0,0},{0,0,0,0},{0,0,0,0},{0,0,0,0}};
#pragma unroll
      for (int m = 0; m < 4; ++m) {
        short8 af = *(const short8*)&lw[(g * 64 + m * 16 + l15) * CWP + quad * 8];
        a2[m] = __builtin_amdgcn_mfma_f32_16x16x32_bf16(af, yb0, a2[m], 0, 0, 0);
      }
#pragma unroll
      for (int m = 0; m < 4; ++m) {
        short8 af = *(const short8*)&lw[(g * 64 + m * 16 + l15) * CWP + 32 + quad * 8];
        a2[m] = __builtin_amdgcn_mfma_f32_16x16x32_bf16(af, yb1, a2[m], 0, 0, 0);
      }
      if (w < W_) {
#pragma unroll
        for (int m = 0; m < 4; ++m) {
          int o = g * 64 + m * 16 + quad * 4;
          float4 bv = *(const float4*)(bias + o);
          ob[(size_t)(o + 0) * HW_] = a2[m].x + bv.x;
          ob[(size_t)(o + 1) * HW_] = a2[m].y + bv.y;
          ob[(size_t)(o + 2) * HW_] = a2[m].z + bv.z;
          ob[(size_t)(o + 3) * HW_] = a2[m].w + bv.w;
        }
      }
    }
  }
}

extern "C" void kernel_launch(void* const* d_in, const int* in_sizes, int n_in,
                              void* d_out, int out_size, void* d_ws, size_t ws_size,
                              hipStream_t stream) {
  const float* x     = (const float*)d_in[0];
  const float* first = (const float*)d_in[1];
  const float* core  = (const float*)d_in[2];
  const float* last  = (const float*)d_in[3];
  const float* bias  = (const float*)d_in[4];
  float* out = (float*)d_out;
  unsigned short* ws16 = (unsigned short*)d_ws;

  prep_kernel<<<272, 256, 0, stream>>>(first, core, last, ws16);
  stageA_kernel<<<B_ * HP_, 256, 0, stream>>>(x, ws16);
  fusedBC_kernel<<<256, 512, 0, stream>>>(ws16, bias, out);
}